// Round 1
// baseline (1495.134 us; speedup 1.0000x reference)
//
#include <hip/hip_runtime.h>

#define B_ 4
#define L_ 2048
#define H_ 16
#define E_ 64
#define D_ 64
#define S_ 2048
#define LDP 72   // padded LDS row length (bf16 elems) for the wave-private P tile

typedef __bf16 bf16x8 __attribute__((ext_vector_type(8)));
typedef __bf16 bf16x4 __attribute__((ext_vector_type(4)));
typedef float  f32x4  __attribute__((ext_vector_type(4)));

// ---------------- pre-kernel 1: Q,K f32 [B,L,H,64] -> bf16 [B,H,L,64] ----------------
__global__ __launch_bounds__(256) void convert_qk(
    const float* __restrict__ Q, const float* __restrict__ K,
    __bf16* __restrict__ Qb, __bf16* __restrict__ Kb)
{
    const int g = blockIdx.x * 256 + threadIdx.x;     // enumerates [b][l][h][e4]
    const float* src = blockIdx.y ? K : Q;
    __bf16* dst = blockIdx.y ? Kb : Qb;
    const int e4 = g & 15;
    const int h  = (g >> 4) & (H_ - 1);
    const int l  = (g >> 8) & (L_ - 1);
    const int b  = g >> 19;
    f32x4 v = *(const f32x4*)(src + (size_t)g * 4);   // coalesced 16B reads
    bf16x4 o;
    o[0] = (__bf16)v[0]; o[1] = (__bf16)v[1];
    o[2] = (__bf16)v[2]; o[3] = (__bf16)v[3];
    *(bf16x4*)(dst + (((size_t)(b * H_ + h) * L_ + l) * E_ + e4 * 4)) = o;
}

// ---------------- pre-kernel 2: V f32 [B,L,H,64] -> bf16 V^T [B,H,64,L] ----------------
__global__ __launch_bounds__(256) void convert_vt(
    const float* __restrict__ V, __bf16* __restrict__ Vt)
{
    __shared__ __bf16 T[64 * 68];
    const int tid = threadIdx.x;
    const int lt  = blockIdx.x & 31;     // 64-row l-tile
    const int bh  = blockIdx.x >> 5;
    const int b = bh >> 4, h = bh & 15;
    const int l0 = lt * 64;
    for (int i = 0; i < 4; ++i) {
        const int lr = (tid >> 4) + 16 * i;
        const int c4 = (tid & 15) * 4;
        f32x4 v = *(const f32x4*)(V + ((size_t)(b * L_ + l0 + lr) * H_ + h) * D_ + c4);
        bf16x4 o;
        o[0] = (__bf16)v[0]; o[1] = (__bf16)v[1];
        o[2] = (__bf16)v[2]; o[3] = (__bf16)v[3];
        *(bf16x4*)&T[lr * 68 + c4] = o;
    }
    __syncthreads();
    for (int i = 0; i < 4; ++i) {
        const int d  = (tid >> 4) + 16 * i;
        const int s4 = (tid & 15) * 4;
        bf16x4 o;
        o[0] = T[(s4 + 0) * 68 + d];
        o[1] = T[(s4 + 1) * 68 + d];
        o[2] = T[(s4 + 2) * 68 + d];
        o[3] = T[(s4 + 3) * 68 + d];
        *(bf16x4*)(Vt + ((size_t)bh * 64 + d) * L_ + l0 + s4) = o;  // coalesced 8B writes
    }
}

// ---------------- main kernel: no barriers, no K/V staging ----------------
__global__ __launch_bounds__(256) void fullattn_kernel(
    const __bf16* __restrict__ Qb, const __bf16* __restrict__ Kb,
    const __bf16* __restrict__ Vt, float* __restrict__ Vout,
    float* __restrict__ Aout)
{
    __shared__ __bf16 P_lds[64 * LDP];   // wave-private 16-row slices, never barriered

    const int tid  = threadIdx.x;
    const int wave = tid >> 6;
    const int lane = tid & 63;
    const int ln15 = lane & 15;
    const int quad = lane >> 4;

    // big q-tiles dispatch first to remove the causal work-skew tail
    const int bh = blockIdx.x & 63;
    const int qt = 31 - (blockIdx.x >> 6);
    const int b  = bh >> 4;
    const int h  = bh & 15;
    const int q0 = qt * 64;
    const int nb = qt + 1;

    // exp(s*0.125 - 16) == exp2(s*C1 + C2)
    const float C1 = 0.125f * 1.44269504089f;
    const float C2 = -16.0f * 1.44269504089f;

    const __bf16* Qh = Qb + (size_t)bh * L_ * E_;
    const __bf16* Kh = Kb + (size_t)bh * L_ * E_;
    const __bf16* Vh = Vt + (size_t)bh * 64 * L_;

    // Q fragments (A-operand): row = q0+16w+ln15, k = quad*8 + 32f + j
    bf16x8 qfrag[2];
    {
        const __bf16* qp = Qh + (size_t)(q0 + 16 * wave + ln15) * E_ + quad * 8;
        qfrag[0] = *(const bf16x8*)(qp);
        qfrag[1] = *(const bf16x8*)(qp + 32);
    }

    // ============ pass 1: row sums of exp (B-frags straight from global, L1/L2-hot) ============
    float sums[4] = {0.f, 0.f, 0.f, 0.f};
    for (int kb = 0; kb < nb; ++kb) {
        const bool diag = (kb == qt);
        const __bf16* kp = Kh + (size_t)(kb * 64 + ln15) * E_ + quad * 8;
#pragma unroll
        for (int t = 0; t < 4; ++t) {
            const __bf16* kpt = kp + t * 16 * E_;
            f32x4 acc = {0.f, 0.f, 0.f, 0.f};
            acc = __builtin_amdgcn_mfma_f32_16x16x32_bf16(qfrag[0], *(const bf16x8*)(kpt), acc, 0, 0, 0);
            acc = __builtin_amdgcn_mfma_f32_16x16x32_bf16(qfrag[1], *(const bf16x8*)(kpt + 32), acc, 0, 0, 0);
            const int scol = 16 * t + ln15;
#pragma unroll
            for (int r = 0; r < 4; ++r) {
                const int lrow = 16 * wave + quad * 4 + r;
                float p = (diag && (scol > lrow)) ? 0.0f
                        : __builtin_amdgcn_exp2f(fmaf(acc[r], C1, C2));
                sums[r] += p;
            }
        }
    }
    float rinv[4];
#pragma unroll
    for (int r = 0; r < 4; ++r) {
        float s = sums[r];
        s += __shfl_xor(s, 1);
        s += __shfl_xor(s, 2);
        s += __shfl_xor(s, 4);
        s += __shfl_xor(s, 8);
        rinv[r] = 1.0f / s;
    }

    // ============ pass 2: A = P/l (f32 straight from regs), O += P*V ============
    f32x4 oacc[4] = {{0.f,0.f,0.f,0.f},{0.f,0.f,0.f,0.f},
                     {0.f,0.f,0.f,0.f},{0.f,0.f,0.f,0.f}};
    const size_t arow0 = (size_t)bh * L_ + q0;

    for (int kb = 0; kb < nb; ++kb) {
        const bool diag = (kb == qt);
        const __bf16* kp = Kh + (size_t)(kb * 64 + ln15) * E_ + quad * 8;
#pragma unroll
        for (int t = 0; t < 4; ++t) {
            const __bf16* kpt = kp + t * 16 * E_;
            f32x4 acc = {0.f, 0.f, 0.f, 0.f};
            acc = __builtin_amdgcn_mfma_f32_16x16x32_bf16(qfrag[0], *(const bf16x8*)(kpt), acc, 0, 0, 0);
            acc = __builtin_amdgcn_mfma_f32_16x16x32_bf16(qfrag[1], *(const bf16x8*)(kpt + 32), acc, 0, 0, 0);
            const int scol = 16 * t + ln15;
#pragma unroll
            for (int r = 0; r < 4; ++r) {
                const int lrow = 16 * wave + quad * 4 + r;
                float p = (diag && (scol > lrow)) ? 0.0f
                        : __builtin_amdgcn_exp2f(fmaf(acc[r], C1, C2));
                const float a = p * rinv[r];
                // 16 lanes * 4B contiguous = 64B segments, 4 rows per instr
                Aout[(arow0 + lrow) * S_ + kb * 64 + scol] = a;
                P_lds[lrow * LDP + scol] = (__bf16)a;   // wave-private relayout tile
            }
        }

        // PV: A-op = P (wave-private LDS, same-wave ordering via lgkmcnt, no barrier),
        //     B-op = V^T fragments straight from global (16B/lane, 64B segments, L1-hot)
        bf16x8 afr0 = *(const bf16x8*)&P_lds[(16 * wave + ln15) * LDP + quad * 8];
        bf16x8 afr1 = *(const bf16x8*)&P_lds[(16 * wave + ln15) * LDP + quad * 8 + 32];
        const __bf16* vp = Vh + (size_t)ln15 * L_ + kb * 64 + quad * 8;
#pragma unroll
        for (int t = 0; t < 4; ++t) {
            const __bf16* vpt = vp + (size_t)t * 16 * L_;
            oacc[t] = __builtin_amdgcn_mfma_f32_16x16x32_bf16(afr0, *(const bf16x8*)(vpt), oacc[t], 0, 0, 0);
            oacc[t] = __builtin_amdgcn_mfma_f32_16x16x32_bf16(afr1, *(const bf16x8*)(vpt + 32), oacc[t], 0, 0, 0);
        }
    }

    // zero-fill A columns [nb*64, 2048)
    {
        const int c0 = nb * 64;
        const f32x4 z = {0.f, 0.f, 0.f, 0.f};
        for (int r = 0; r < 16; ++r) {
            float* ap = Aout + (arow0 + 16 * wave + r) * S_;
            for (int c = c0 + lane * 4; c < S_; c += 256)
                *(f32x4*)(ap + c) = z;
        }
    }

    // V output [B,L,H,D]
#pragma unroll
    for (int t = 0; t < 4; ++t)
#pragma unroll
        for (int r = 0; r < 4; ++r) {
            const int l = q0 + 16 * wave + quad * 4 + r;
            Vout[((size_t)(b * L_ + l) * H_ + h) * D_ + 16 * t + ln15] = oacc[t][r];
        }
}

extern "C" void kernel_launch(void* const* d_in, const int* in_sizes, int n_in,
                              void* d_out, int out_size, void* d_ws, size_t ws_size,
                              hipStream_t stream) {
    const float* Q = (const float*)d_in[0];
    const float* K = (const float*)d_in[1];
    const float* V = (const float*)d_in[2];
    float* Vout = (float*)d_out;
    float* Aout = Vout + (size_t)B_ * L_ * H_ * D_;   // V first, then A

    // bf16 workspace: Qb, Kb [B,H,L,64]; Vt [B,H,64,L]  (3 * 16.78 MB = 50.4 MB)
    __bf16* Qb = (__bf16*)d_ws;
    __bf16* Kb = Qb + (size_t)B_ * H_ * L_ * E_;
    __bf16* Vt = Kb + (size_t)B_ * H_ * L_ * E_;

    hipLaunchKernelGGL(convert_qk, dim3((B_ * L_ * H_ * E_) / (256 * 4), 2), dim3(256),
                       0, stream, Q, K, Qb, Kb);
    hipLaunchKernelGGL(convert_vt, dim3(B_ * H_ * (L_ / 64)), dim3(256),
                       0, stream, V, Vt);
    hipLaunchKernelGGL(fullattn_kernel, dim3(B_ * H_ * (L_ / 64)), dim3(256),
                       0, stream, Qb, Kb, Vt, Vout, Aout);
}

// Round 2
// 1306.423 us; speedup vs baseline: 1.1444x; 1.1444x over previous
//
#include <hip/hip_runtime.h>

#define B_ 4
#define L_ 2048
#define H_ 16
#define E_ 64
#define D_ 64
#define S_ 2048
#define LDP 72   // padded LDS row (bf16 elems) for the wave-private P tile

typedef __bf16 bf16x8 __attribute__((ext_vector_type(8)));
typedef __bf16 bf16x4 __attribute__((ext_vector_type(4)));
typedef float  f32x4  __attribute__((ext_vector_type(4)));

// exp(s*0.125 - 16) == exp2(s*C1 + C2)
#define C1f (0.125f * 1.44269504089f)
#define C2f (-16.0f * 1.44269504089f)

// Fragment-swizzled layout for Q/K: X_sw[((bh*32+tile)*8 + f)*64 + lane] (16B units),
// f = t*2+half, holds X[b, tile*64 + t*16 + (lane&15), h, (lane>>4)*8 + half*32 + j]
__global__ __launch_bounds__(256) void convert_qk_sw(
    const float* __restrict__ Q, const float* __restrict__ K,
    __bf16* __restrict__ Qsw, __bf16* __restrict__ Ksw)
{
    const int g = blockIdx.x * 256 + threadIdx.x;   // (bh, tile, f, lane)
    const float* src = blockIdx.y ? K : Q;
    __bf16* dst = blockIdx.y ? Ksw : Qsw;
    const int l  = g & 63;
    const int f  = (g >> 6) & 7;
    const int tl = (g >> 9) & 31;
    const int bh = g >> 14;
    const int b = bh >> 4, h = bh & 15;
    const int s  = tl * 64 + (f >> 1) * 16 + (l & 15);
    const int e0 = (l >> 4) * 8 + (f & 1) * 32;
    const float* sp = src + (((size_t)(b * L_ + s) * H_ + h) * E_ + e0);
    f32x4 x = *(const f32x4*)sp;
    f32x4 y = *(const f32x4*)(sp + 4);
    bf16x8 o;
    o[0]=(__bf16)x[0]; o[1]=(__bf16)x[1]; o[2]=(__bf16)x[2]; o[3]=(__bf16)x[3];
    o[4]=(__bf16)y[0]; o[5]=(__bf16)y[1]; o[6]=(__bf16)y[2]; o[7]=(__bf16)y[3];
    *(bf16x8*)(dst + (size_t)g * 8) = o;
}

// V fragments (B-op of PV): V_sw[((bh*32+kb)*8 + f)*64 + lane] holds
// V[b, kb*64 + (lane>>4)*8 + (f&1)*32 + j, h, (f>>1)*16 + (lane&15)]
__global__ __launch_bounds__(256) void convert_v_sw(
    const float* __restrict__ V, __bf16* __restrict__ Vsw)
{
    __shared__ __bf16 T[64 * 68];
    const int tid = threadIdx.x;
    const int tl  = blockIdx.x & 31;
    const int bh  = blockIdx.x >> 5;
    const int b = bh >> 4, h = bh & 15;
    const int l0 = tl * 64;
    for (int i = 0; i < 4; ++i) {
        const int lr = (tid >> 4) + 16 * i;
        const int c4 = (tid & 15) * 4;
        f32x4 v = *(const f32x4*)(V + ((size_t)(b * L_ + l0 + lr) * H_ + h) * D_ + c4);
        bf16x4 o;
        o[0]=(__bf16)v[0]; o[1]=(__bf16)v[1]; o[2]=(__bf16)v[2]; o[3]=(__bf16)v[3];
        *(bf16x4*)&T[lr * 68 + c4] = o;
    }
    __syncthreads();
    for (int i = 0; i < 2; ++i) {
        const int o = i * 256 + tid;
        const int l = o & 63, f = (o >> 6) & 7;
        const int d  = (f >> 1) * 16 + (l & 15);
        const int s0 = (l >> 4) * 8 + (f & 1) * 32;
        bf16x8 vv;
#pragma unroll
        for (int j = 0; j < 8; ++j) vv[j] = T[(s0 + j) * 68 + d];
        *(bf16x8*)(Vsw + ((((size_t)bh * 32 + tl) * 8 + f) * 64 + l) * 8) = vv;
    }
}

// load 8 MFMA fragments (one 64-wide K/V block) with immediate offsets
#define LOADF(dst, base) do {                                               \
    const __bf16* _p0 = (base); const __bf16* _p1 = _p0 + 2048;             \
    dst[0]=*(const bf16x8*)(_p0);      dst[1]=*(const bf16x8*)(_p0+512);    \
    dst[2]=*(const bf16x8*)(_p0+1024); dst[3]=*(const bf16x8*)(_p0+1536);   \
    dst[4]=*(const bf16x8*)(_p1);      dst[5]=*(const bf16x8*)(_p1+512);    \
    dst[6]=*(const bf16x8*)(_p1+1024); dst[7]=*(const bf16x8*)(_p1+1536);   \
} while (0)

// ---------------- pass 1: row-sum reciprocals ----------------
__global__ __launch_bounds__(256) void attn_sums(
    const __bf16* __restrict__ Qsw, const __bf16* __restrict__ Ksw,
    float* __restrict__ Rinv)
{
    const int tid = threadIdx.x, wave = tid >> 6, lane = tid & 63;
    const int ln15 = lane & 15, quad = lane >> 4;
    const int bh = blockIdx.x & 63;
    const int qt = 31 - (blockIdx.x >> 6);        // big tiles first
    const size_t tileId = (size_t)bh * 32 + qt;

    bf16x8 qfrag[2];
    {
        const __bf16* qp = Qsw + (tileId * 8 + 2 * wave) * 512 + (size_t)lane * 8;
        qfrag[0] = *(const bf16x8*)qp;
        qfrag[1] = *(const bf16x8*)(qp + 512);
    }
    const __bf16* Kh = Ksw + (size_t)bh * 32 * 4096 + (size_t)lane * 8;

    bf16x8 kf[8], kn[8];
    LOADF(kf, Kh);
    float sums[4] = {0.f, 0.f, 0.f, 0.f};
    for (int kb = 0; kb < qt; ++kb) {             // clean blocks: no masking
        LOADF(kn, Kh + (size_t)(kb + 1) * 4096);
#pragma unroll
        for (int t = 0; t < 4; ++t) {
            f32x4 acc = {0.f, 0.f, 0.f, 0.f};
            acc = __builtin_amdgcn_mfma_f32_16x16x32_bf16(qfrag[0], kf[2*t],   acc, 0, 0, 0);
            acc = __builtin_amdgcn_mfma_f32_16x16x32_bf16(qfrag[1], kf[2*t+1], acc, 0, 0, 0);
#pragma unroll
            for (int r = 0; r < 4; ++r)
                sums[r] += __builtin_amdgcn_exp2f(fmaf(acc[r], C1f, C2f));
        }
#pragma unroll
        for (int i = 0; i < 8; ++i) kf[i] = kn[i];
    }
    // diagonal block (kb == qt), masked
#pragma unroll
    for (int t = 0; t < 4; ++t) {
        f32x4 acc = {0.f, 0.f, 0.f, 0.f};
        acc = __builtin_amdgcn_mfma_f32_16x16x32_bf16(qfrag[0], kf[2*t],   acc, 0, 0, 0);
        acc = __builtin_amdgcn_mfma_f32_16x16x32_bf16(qfrag[1], kf[2*t+1], acc, 0, 0, 0);
        const int scol = 16 * t + ln15;
#pragma unroll
        for (int r = 0; r < 4; ++r) {
            const int lrow = 16 * wave + quad * 4 + r;
            float p = (scol > lrow) ? 0.0f
                    : __builtin_amdgcn_exp2f(fmaf(acc[r], C1f, C2f));
            sums[r] += p;
        }
    }
    float out[4];
#pragma unroll
    for (int r = 0; r < 4; ++r) {
        float s = sums[r];
        s += __shfl_xor(s, 1);
        s += __shfl_xor(s, 2);
        s += __shfl_xor(s, 4);
        s += __shfl_xor(s, 8);
        out[r] = 1.0f / s;
    }
    if (ln15 == 0) {
#pragma unroll
        for (int r = 0; r < 4; ++r)
            Rinv[tileId * 64 + 16 * wave + quad * 4 + r] = out[r];
    }
}

// ---------------- pass 2: A = P/l (nt stores), O = A*V ----------------
__global__ __launch_bounds__(256) void attn_out(
    const __bf16* __restrict__ Qsw, const __bf16* __restrict__ Ksw,
    const __bf16* __restrict__ Vsw, const float* __restrict__ Rinv,
    float* __restrict__ Vout, float* __restrict__ Aout)
{
    __shared__ __bf16 P_lds[64 * LDP];

    const int tid = threadIdx.x, wave = tid >> 6, lane = tid & 63;
    const int ln15 = lane & 15, quad = lane >> 4;
    const int bh = blockIdx.x & 63;
    const int qt = 31 - (blockIdx.x >> 6);
    const int b = bh >> 4, h = bh & 15;
    const int q0 = qt * 64;
    const size_t tileId = (size_t)bh * 32 + qt;

    bf16x8 qfrag[2];
    {
        const __bf16* qp = Qsw + (tileId * 8 + 2 * wave) * 512 + (size_t)lane * 8;
        qfrag[0] = *(const bf16x8*)qp;
        qfrag[1] = *(const bf16x8*)(qp + 512);
    }
    float rinv[4];
#pragma unroll
    for (int r = 0; r < 4; ++r)
        rinv[r] = Rinv[tileId * 64 + 16 * wave + quad * 4 + r];

    const __bf16* Kh = Ksw + (size_t)bh * 32 * 4096 + (size_t)lane * 8;
    const __bf16* Vh = Vsw + (size_t)bh * 32 * 4096 + (size_t)lane * 8;

    const size_t arow0 = (size_t)bh * L_ + q0;
    float* ap[4];
#pragma unroll
    for (int r = 0; r < 4; ++r)
        ap[r] = Aout + (arow0 + 16 * wave + quad * 4 + r) * S_ + ln15;

    const int plw = (16 * wave + quad * 4) * LDP + ln15;   // P write base (elems)
    const int plr = (16 * wave + ln15) * LDP + quad * 8;   // P A-frag read base

    f32x4 oacc[4] = {{0.f,0.f,0.f,0.f},{0.f,0.f,0.f,0.f},
                     {0.f,0.f,0.f,0.f},{0.f,0.f,0.f,0.f}};
    bf16x8 kf[8], kn[8], vf[8];
    LOADF(kf, Kh);

    for (int kb = 0; kb < qt; ++kb) {             // clean blocks
        LOADF(vf, Vh + (size_t)kb * 4096);
        LOADF(kn, Kh + (size_t)(kb + 1) * 4096);
#pragma unroll
        for (int t = 0; t < 4; ++t) {
            f32x4 acc = {0.f, 0.f, 0.f, 0.f};
            acc = __builtin_amdgcn_mfma_f32_16x16x32_bf16(qfrag[0], kf[2*t],   acc, 0, 0, 0);
            acc = __builtin_amdgcn_mfma_f32_16x16x32_bf16(qfrag[1], kf[2*t+1], acc, 0, 0, 0);
#pragma unroll
            for (int r = 0; r < 4; ++r) {
                float a = __builtin_amdgcn_exp2f(fmaf(acc[r], C1f, C2f)) * rinv[r];
                __builtin_nontemporal_store(a, ap[r] + 16 * t);
                P_lds[plw + r * LDP + 16 * t] = (__bf16)a;
            }
        }
        bf16x8 afr0 = *(const bf16x8*)&P_lds[plr];
        bf16x8 afr1 = *(const bf16x8*)&P_lds[plr + 32];
#pragma unroll
        for (int t = 0; t < 4; ++t) {
            oacc[t] = __builtin_amdgcn_mfma_f32_16x16x32_bf16(afr0, vf[2*t],   oacc[t], 0, 0, 0);
            oacc[t] = __builtin_amdgcn_mfma_f32_16x16x32_bf16(afr1, vf[2*t+1], oacc[t], 0, 0, 0);
        }
#pragma unroll
        for (int i = 0; i < 8; ++i) kf[i] = kn[i];
#pragma unroll
        for (int r = 0; r < 4; ++r) ap[r] += 64;
    }

    // diagonal block (kb == qt), masked
    LOADF(vf, Vh + (size_t)qt * 4096);
#pragma unroll
    for (int t = 0; t < 4; ++t) {
        f32x4 acc = {0.f, 0.f, 0.f, 0.f};
        acc = __builtin_amdgcn_mfma_f32_16x16x32_bf16(qfrag[0], kf[2*t],   acc, 0, 0, 0);
        acc = __builtin_amdgcn_mfma_f32_16x16x32_bf16(qfrag[1], kf[2*t+1], acc, 0, 0, 0);
        const int scol = 16 * t + ln15;
#pragma unroll
        for (int r = 0; r < 4; ++r) {
            const int lrow = 16 * wave + quad * 4 + r;
            float a = (scol > lrow) ? 0.0f
                    : __builtin_amdgcn_exp2f(fmaf(acc[r], C1f, C2f)) * rinv[r];
            __builtin_nontemporal_store(a, ap[r] + 16 * t);
            P_lds[plw + r * LDP + 16 * t] = (__bf16)a;
        }
    }
    {
        bf16x8 afr0 = *(const bf16x8*)&P_lds[plr];
        bf16x8 afr1 = *(const bf16x8*)&P_lds[plr + 32];
#pragma unroll
        for (int t = 0; t < 4; ++t) {
            oacc[t] = __builtin_amdgcn_mfma_f32_16x16x32_bf16(afr0, vf[2*t],   oacc[t], 0, 0, 0);
            oacc[t] = __builtin_amdgcn_mfma_f32_16x16x32_bf16(afr1, vf[2*t+1], oacc[t], 0, 0, 0);
        }
    }

    // zero-fill A columns [(qt+1)*64, 2048)
    {
        const int c0 = (qt + 1) * 64;
        const f32x4 z = {0.f, 0.f, 0.f, 0.f};
        for (int r = 0; r < 16; ++r) {
            float* zp = Aout + (arow0 + 16 * wave + r) * S_;
            for (int c = c0 + lane * 4; c < S_; c += 256)
                __builtin_nontemporal_store(z, (f32x4*)(zp + c));
        }
    }

    // V output [B,L,H,D]
#pragma unroll
    for (int r = 0; r < 4; ++r) {
        float* vo = Vout + (((size_t)(b * L_ + q0 + 16 * wave + quad * 4 + r)) * H_ + h) * D_ + ln15;
#pragma unroll
        for (int t = 0; t < 4; ++t)
            __builtin_nontemporal_store(oacc[t][r], vo + 16 * t);
    }
}

extern "C" void kernel_launch(void* const* d_in, const int* in_sizes, int n_in,
                              void* d_out, int out_size, void* d_ws, size_t ws_size,
                              hipStream_t stream) {
    const float* Q = (const float*)d_in[0];
    const float* K = (const float*)d_in[1];
    const float* V = (const float*)d_in[2];
    float* Vout = (float*)d_out;
    float* Aout = Vout + (size_t)B_ * L_ * H_ * D_;   // V first, then A

    // workspace: Qsw, Ksw, Vsw (16.78 MB each) + Rinv (512 KB)
    __bf16* Qsw = (__bf16*)d_ws;
    __bf16* Ksw = Qsw + (size_t)B_ * H_ * L_ * E_;
    __bf16* Vsw = Ksw + (size_t)B_ * H_ * L_ * E_;
    float*  Rinv = (float*)(Vsw + (size_t)B_ * H_ * L_ * D_);

    hipLaunchKernelGGL(convert_qk_sw, dim3(4096, 2), dim3(256), 0, stream, Q, K, Qsw, Ksw);
    hipLaunchKernelGGL(convert_v_sw, dim3(B_ * H_ * (L_ / 64)), dim3(256), 0, stream, V, Vsw);
    hipLaunchKernelGGL(attn_sums, dim3(B_ * H_ * (L_ / 64)), dim3(256), 0, stream, Qsw, Ksw, Rinv);
    hipLaunchKernelGGL(attn_out, dim3(B_ * H_ * (L_ / 64)), dim3(256), 0, stream,
                       Qsw, Ksw, Vsw, Rinv, Vout, Aout);
}